// Round 1
// baseline (596.754 us; speedup 1.0000x reference)
//
#include <hip/hip_runtime.h>

#define BB 256
#define TT 200
#define QQ 1024
#define ROWS (BB * (TT - 1))   // 50944

__global__ void zero_out_kernel(float* out) {
    out[0] = 0.0f;
}

// batch rows are one-hot derived: each (b,t) row of batch[:, 1:, :]
// (2048 floats) has exactly ONE nonzero, value 1.0:
//   index < 1024  -> correct = 1, qid = index
//   index >= 1024 -> correct = 0, qid = index - 1024
// probs = pred_row[qid] (bitwise exact), answers = correct.
//
// v2: 4 rows in flight per wave. The previous version had ONE outstanding
// 1KB load per wave (load -> __any -> break = full vmcnt(0) round trip per
// chunk), i.e. latency-bound at 1 request deep. Here each super-iteration
// issues up to 4 independent 1KB chunk loads (one per row-slot) before any
// test consumes data: 4x memory-level parallelism, same early-exit traffic
// (~235 MB expected instead of 417 MB full-batch).
// Slots are the SAME 4 consecutive grid-stride steps as before (r + s*num_waves),
// processed in the same increasing-k order, so per-lane accumulation order
// and therefore the final sum stay bitwise identical.
__global__ __launch_bounds__(256) void loss_kernel(
        const float* __restrict__ pred,
        const float* __restrict__ batch,
        float* __restrict__ out) {
    const int lane = threadIdx.x & 63;
    const int wave_in_block = threadIdx.x >> 6;          // 0..3
    const int wave_id = blockIdx.x * 4 + wave_in_block;
    const int num_waves = gridDim.x * 4;

    float acc = 0.0f;

    for (int r0 = wave_id; r0 < ROWS; r0 += num_waves * 4) {
        int          found[4];
        bool         done[4];     // wave-uniform by construction
        const float4* c4s[4];
        const float*  prows[4];

        #pragma unroll
        for (int s = 0; s < 4; ++s) {
            const int r = r0 + s * num_waves;
            found[s] = -1;
            done[s]  = (r >= ROWS);
            if (!done[s]) {
                const int b = r / (TT - 1);
                const int t = r - b * (TT - 1);
                c4s[s]   = (const float4*)(batch + (size_t)(b * TT + t + 1) * (2 * QQ));
                prows[s] = pred + (size_t)(b * TT + t) * QQ;
            } else {
                c4s[s]   = (const float4*)batch;  // never dereferenced (done)
                prows[s] = pred;
            }
        }

        #pragma unroll 1
        for (int j = 0; j < 8; ++j) {
            if (done[0] && done[1] && done[2] && done[3]) break;

            const int idx = lane + j * 64;   // float4 index 0..511

            // Issue phase: up to 4 independent 1KB loads, no data consumed yet.
            float4 c[4];
            #pragma unroll
            for (int s = 0; s < 4; ++s) {
                if (!done[s]) c[s] = c4s[s][idx];
            }

            // Test phase: consume in issue order (staged vmcnt waits).
            #pragma unroll
            for (int s = 0; s < 4; ++s) {
                if (!done[s]) {
                    int f = found[s];
                    if (c[s].x != 0.0f) f = 4 * idx + 0;
                    if (c[s].y != 0.0f) f = 4 * idx + 1;
                    if (c[s].z != 0.0f) f = 4 * idx + 2;
                    if (c[s].w != 0.0f) f = 4 * idx + 3;
                    found[s] = f;
                    done[s]  = (__any(f >= 0) != 0);
                }
            }
        }

        // Exactly one lane per (active) row has found >= 0.
        #pragma unroll
        for (int s = 0; s < 4; ++s) {
            if (found[s] >= 0) {
                const float a   = (found[s] < QQ) ? 1.0f : 0.0f;   // correct
                const int   qid = (found[s] < QQ) ? found[s] : found[s] - QQ;
                const float p   = prows[s][qid];                   // == probs, exact
                if (p > 0.0f) {
                    acc -= a * logf(p) + (1.0f - a) * log1pf(-p);
                }
                // else: mask false -> contributes 0
            }
        }
    }

    // Reduce acc across the 64-lane wave, then across the block's 4 waves.
    #pragma unroll
    for (int off = 32; off > 0; off >>= 1) {
        acc += __shfl_xor(acc, off, 64);
    }

    __shared__ float smem[4];
    if (lane == 0) smem[wave_in_block] = acc;
    __syncthreads();
    if (threadIdx.x == 0) {
        atomicAdd(out, smem[0] + smem[1] + smem[2] + smem[3]);
    }
}

extern "C" void kernel_launch(void* const* d_in, const int* in_sizes, int n_in,
                              void* d_out, int out_size, void* d_ws, size_t ws_size,
                              hipStream_t stream) {
    const float* pred  = (const float*)d_in[0];   // (B, T, Q) fp32
    const float* batch = (const float*)d_in[1];   // (B, T, 2Q) fp32
    float* out = (float*)d_out;                   // (1,) fp32

    zero_out_kernel<<<1, 1, 0, stream>>>(out);

    const int blocks = 2048;   // 8192 waves; 4 rows in flight per wave
    loss_kernel<<<blocks, 256, 0, stream>>>(pred, batch, out);
}